// Round 14
// baseline (245.928 us; speedup 1.0000x reference)
//
#include <hip/hip_runtime.h>
#include <cmath>

// GCN 2-layer forward on MI355X — round 19: r13 (241.6us, best) + 3 micro-opts:
// (1) bscatter: ECHUNK 2048 (782 blocks) + dst held in regs between passes
//     (kills the 6.4MB dst re-read);
// (2) bbuild: 512 threads (2x faster pair passes, scan kept 256-wide);
// (3) agg128g2 Phase-B Cs stride 64->72 shorts (8-way -> 4-way store conflict,
//     144B row stride stays 16B-aligned for the uint4 read-back).
// Pipeline: memset -> bscatter||castW -> bbuild -> gemm1 -> agg128+gemm2 ->
//           agg64+lsm.   (6 dispatches)
// Lesson bank: no mem||mem fusion (r4/r5/r10), no global node atomics (r4/r7),
// no cross-block producer/consumer (r6), keep castW pre-convert (r9),
// no column slicing (r11: 3.9x FETCH amplification).

#define THREADS 256
#define BSHIFT 8                      // 256 nodes per bucket
#define MAXB 512                      // >= ceil(N/256)
#define SLAB_E 8192                   // pairs slots per bucket
#define SLAB_C 9984                   // csr slots per bucket (SLAB_E + 256*7 pad)
#define NB_CAST 96                    // castW blocks (96*256 = 24576 weights)
#define ECHUNK 2048                   // edges per chunk (bscatter)
#define CSP 72                        // Cs padded row stride (shorts): 144B, 16B-aligned

__device__ __forceinline__ unsigned short f2bf(float f) {
    union { float f; unsigned u; } v; v.f = f;
    unsigned r = v.u + 0x7FFFu + ((v.u >> 16) & 1u);   // round-nearest-even
    return (unsigned short)(r >> 16);
}
__device__ __forceinline__ float bf_lo(unsigned u) {
    union { unsigned u; float f; } v; v.u = u << 16; return v.f;
}
__device__ __forceinline__ float bf_hi(unsigned u) {
    union { unsigned u; float f; } v; v.u = u & 0xFFFF0000u; return v.f;
}

typedef __attribute__((ext_vector_type(8))) short bf16x8;
typedef __attribute__((ext_vector_type(4))) float f32x4;

// ==== K1: castW (blocks 0..95) || slab scatter (blocks 96..) ====
// Scatter: dst int4s held in registers across both passes (single global read).
__global__ __launch_bounds__(256) void k_bscatter(const int* __restrict__ src,
                                                  const int* __restrict__ dst, int E, int B,
                                                  const float* __restrict__ W1,
                                                  const float* __restrict__ W2,
                                                  unsigned short* __restrict__ Wt1,
                                                  unsigned short* __restrict__ Wt2,
                                                  int* __restrict__ bfill,
                                                  unsigned* __restrict__ pairs) {
    const int tid = threadIdx.x;
    if (blockIdx.x < NB_CAST) {
        // Wt1[n][k] = bf16(W1[k][n]) (128x128), Wt2[n][k] = bf16(W2[k][n]) (64x128)
        int idx = blockIdx.x * 256 + tid;
        if (idx < 16384) {
            int n = idx >> 7, k = idx & 127;
            Wt1[idx] = f2bf(W1[k * 128 + n]);
        } else {
            int t = idx - 16384;
            int n = t >> 7, k = t & 127;
            Wt2[t] = f2bf(W2[k * 64 + n]);
        }
        return;
    }
    __shared__ int lc[MAXB];     // per-block bucket count, then per-bucket rank
    __shared__ int lbase[MAXB];  // reservation base within bucket slab
    const int e0 = (blockIdx.x - NB_CAST) * ECHUNK;
    for (int i = tid; i < MAXB; i += 256) lc[i] = 0;
    __syncthreads();
    int4 d4[2];
    bool ok[2];
#pragma unroll
    for (int k = 0; k < 2; k++) {
        int e = e0 + k * 1024 + tid * 4;            // E % 4 == 0
        ok[k] = (e < E);
        if (ok[k]) {
            d4[k] = *(const int4*)&dst[e];
            atomicAdd(&lc[d4[k].x >> BSHIFT], 1); atomicAdd(&lc[d4[k].y >> BSHIFT], 1);
            atomicAdd(&lc[d4[k].z >> BSHIFT], 1); atomicAdd(&lc[d4[k].w >> BSHIFT], 1);
        }
    }
    __syncthreads();
    for (int b = tid; b < B; b += 256)
        lbase[b] = lc[b] ? atomicAdd(&bfill[b], lc[b]) : 0;
    __syncthreads();
    for (int i = tid; i < MAXB; i += 256) lc[i] = 0;  // reuse as rank
    __syncthreads();
#pragma unroll
    for (int k = 0; k < 2; k++) {
        int e = e0 + k * 1024 + tid * 4;
        if (ok[k]) {
            int4 s4 = *(const int4*)&src[e];
            int b0, r;
            b0 = d4[k].x >> BSHIFT; r = atomicAdd(&lc[b0], 1);
            pairs[(size_t)b0 * SLAB_E + lbase[b0] + r] = ((unsigned)(d4[k].x & 255) << 24) | (unsigned)s4.x;
            b0 = d4[k].y >> BSHIFT; r = atomicAdd(&lc[b0], 1);
            pairs[(size_t)b0 * SLAB_E + lbase[b0] + r] = ((unsigned)(d4[k].y & 255) << 24) | (unsigned)s4.y;
            b0 = d4[k].z >> BSHIFT; r = atomicAdd(&lc[b0], 1);
            pairs[(size_t)b0 * SLAB_E + lbase[b0] + r] = ((unsigned)(d4[k].z & 255) << 24) | (unsigned)s4.z;
            b0 = d4[k].w >> BSHIFT; r = atomicAdd(&lc[b0], 1);
            pairs[(size_t)b0 * SLAB_E + lbase[b0] + r] = ((unsigned)(d4[k].w & 255) << 24) | (unsigned)s4.w;
        }
    }
}

// ==== K2: per-bucket padded-CSR build: one 512-thread block per bucket ====
__global__ __launch_bounds__(512) void k_bbuild(const unsigned* __restrict__ pairs,
                                                const int* __restrict__ bfill, int N,
                                                int* __restrict__ deg,
                                                float* __restrict__ dinv,
                                                int* __restrict__ rowptr,
                                                unsigned* __restrict__ csr_off) {
    __shared__ int ldeg[256], lex[256], lrank[256];
    const int b = blockIdx.x, tid = threadIdx.x;
    const int node0 = b << BSHIFT;
    const unsigned* pb = pairs + (size_t)b * SLAB_E;
    const int cnt_e = bfill[b];
    const int pbase = b * SLAB_C;
    if (tid < 256) ldeg[tid] = 0;
    __syncthreads();
    for (int e = tid; e < cnt_e; e += 512)
        atomicAdd(&ldeg[pb[e] >> 24], 1);
    __syncthreads();
    int v = 0, pd = 0;
    if (tid < 256) {
        v = ldeg[tid];
        pd = (v + 7) & ~7;                       // padded degree
        lex[tid] = pd;
    }
    __syncthreads();
    for (int o = 1; o < 256; o <<= 1) {
        int add = (tid >= o && tid < 256) ? lex[tid - o] : 0;
        __syncthreads();
        if (tid < 256) lex[tid] += add;
        __syncthreads();
    }
    int pexcl = 0;
    if (tid < 256) {
        pexcl = lex[tid] - pd;                   // exclusive scan of padded degrees
        if (node0 + tid < N) {
            deg[node0 + tid] = v;
            dinv[node0 + tid] = rsqrtf((float)(v + 1));
            rowptr[node0 + tid] = pbase + pexcl;
        }
    }
    __syncthreads();
    if (tid < 256) {
        lex[tid] = pexcl;      // keep padded exclusive offsets for the scatter
        lrank[tid] = 0;
    }
    __syncthreads();
    for (int e = tid; e < cnt_e; e += 512) {
        unsigned p = pb[e];
        int loc = p >> 24;
        int r = atomicAdd(&lrank[loc], 1);
        csr_off[pbase + lex[loc] + r] = (p & 0xFFFFFFu) << 8;   // byte offset (256B rows)
    }
    // fill pad slots with the dummy source (row N is all-zeros)
    if (tid < 256)
        for (int p = v; p < pd; p++)
            csr_off[pbase + pexcl + p] = ((unsigned)N) << 8;
}

// ==== gemm1: xw1[M x 128](bf16) = dinv[row] * (x[M x 128] @ Wt1^T) ====
__global__ __launch_bounds__(256) void k_gemm1(const float* __restrict__ A,
                                               const unsigned short* __restrict__ Wt,
                                               const float* __restrict__ dinv,
                                               unsigned short* __restrict__ Out,
                                               unsigned short* __restrict__ zrow,
                                               int M) {
    constexpr int NC = 128, KP = 136;
    __shared__ __align__(16) short Bs[NC * KP];
    const int tid = threadIdx.x;
    const int row0 = blockIdx.x * 64;

    if (blockIdx.x == 0 && tid < NC) zrow[tid] = 0;   // dummy zero row

    for (int f = tid; f < NC * 16; f += 256) {
        int n = f >> 4, c = (f & 15) * 8;
        *(uint4*)&Bs[n * KP + c] = *(const uint4*)&Wt[n * 128 + c];
    }

    const int wave = tid >> 6, lane = tid & 63;
    const int m = lane & 15, quad = lane >> 4;
    const int row = row0 + 16 * wave + m;
    const int rowc = row < M ? row : (M - 1);          // clamp; masked at store

    bf16x8 afr[4];
#pragma unroll
    for (int k = 0; k < 4; k++) {
        float4 lo = *(const float4*)&A[(size_t)rowc * 128 + quad * 8 + 32 * k];
        float4 hi = *(const float4*)&A[(size_t)rowc * 128 + quad * 8 + 32 * k + 4];
        bf16x8 a;
        a[0] = (short)f2bf(lo.x); a[1] = (short)f2bf(lo.y);
        a[2] = (short)f2bf(lo.z); a[3] = (short)f2bf(lo.w);
        a[4] = (short)f2bf(hi.x); a[5] = (short)f2bf(hi.y);
        a[6] = (short)f2bf(hi.z); a[7] = (short)f2bf(hi.w);
        afr[k] = a;
    }
    __syncthreads();    // Bs ready

    constexpr int CT = NC / 16;
    f32x4 acc[CT] = {};
    const short* brow = &Bs[m * KP + quad * 8];
#pragma unroll
    for (int k = 0; k < 4; k++) {
#pragma unroll
        for (int c = 0; c < CT; c++) {
            bf16x8 b = *(const bf16x8*)&brow[(size_t)c * 16 * KP + 32 * k];
            acc[c] = __builtin_amdgcn_mfma_f32_16x16x32_bf16(afr[k], b, acc[c], 0, 0, 0);
        }
    }

    __syncthreads();    // all waves done reading Bs -> reuse as Cs
    short* Cs = Bs;
    const int rbase = 16 * wave + quad * 4;
    float dv[4];
#pragma unroll
    for (int r = 0; r < 4; r++) {
        int gr = row0 + rbase + r;
        dv[r] = dinv[gr < M ? gr : 0];
    }
#pragma unroll
    for (int c = 0; c < CT; c++)
#pragma unroll
        for (int r = 0; r < 4; r++)
            Cs[(rbase + r) * NC + 16 * c + m] = (short)f2bf(acc[c][r] * dv[r]);
    __syncthreads();
    for (int f = tid; f < 64 * NC / 8; f += 256) {
        int r = f / (NC / 8), c = (f % (NC / 8)) * 8;
        if (row0 + r < M)
            *(uint4*)&Out[(size_t)(row0 + r) * NC + c] = *(const uint4*)&Cs[r * NC + c];
    }
}

// ==== FUSED agg128 + gemm2: per block of 16 nodes ====
// Phase A: 4 nodes/wave, 16 lanes/row, uint4 gathers from xw1 (pre-scaled),
// bias+ReLU -> h1 row staged in LDS. Phase B: hw2[16x64] = dinv*(h1 @ Wt2^T),
// wave w -> cols [16w,16w+16); Cs stride 72 (4-way store conflict, 16B-aligned).
__global__ __launch_bounds__(256) void k_agg128g2(const unsigned* __restrict__ csr_off,
                                                  const int* __restrict__ rowptr,
                                                  const int* __restrict__ cnt,
                                                  const float* __restrict__ dinv,
                                                  const unsigned char* __restrict__ xwb,
                                                  const float* __restrict__ bias,
                                                  const unsigned short* __restrict__ Wt2,
                                                  unsigned short* __restrict__ hw2,
                                                  unsigned short* __restrict__ zrow,
                                                  int N) {
    constexpr int KP = 136;
    __shared__ __align__(16) short Bs[64 * KP];   // Wt2 tile (17.4 KB)
    __shared__ __align__(16) short As[16 * KP];   // h1 rows / Cs (4.4 KB)
    const int tid = threadIdx.x;
    const int lane = tid & 63, wave = tid >> 6;
    const int g = lane >> 4, sl = lane & 15;
    const int node0 = blockIdx.x * 16;
    const int i = node0 + wave * 4 + g;
    const bool active = (i < N);
    const int ic = active ? i : 0;

    if (blockIdx.x == 0 && tid < 64) zrow[tid] = 0;   // dummy zero row of hw2

    // stage Wt2 (64 x 128 bf16)
    for (int f = tid; f < 64 * 16; f += 256) {
        int n = f >> 4, c = (f & 15) * 8;
        *(uint4*)&Bs[n * KP + c] = *(const uint4*)&Wt2[n * 128 + c];
    }

    // ---- Phase A: aggregate node i, cols 8sl..8sl+7 ----
    const float di = dinv[ic];
    const int slb = sl * 16;
    uint4 u = *(const uint4*)(xwb + ((size_t)ic << 8) + slb);  // self row (pre-scaled)
    float a0 = bf_lo(u.x), a1 = bf_hi(u.x), a2 = bf_lo(u.y), a3 = bf_hi(u.y);
    float a4 = bf_lo(u.z), a5 = bf_hi(u.z), a6 = bf_lo(u.w), a7 = bf_hi(u.w);
    const int start = rowptr[ic];
    const int pc = active ? ((cnt[ic] + 7) & ~7) : 0;
    unsigned s[8];
#pragma unroll
    for (int k = 0; k < 8; k++) s[k] = csr_off[start + k];
    for (int j = 0; j < pc; j += 8) {
        uint4 uu[8];
#pragma unroll
        for (int k = 0; k < 8; k++) uu[k] = *(const uint4*)(xwb + s[k] + slb);
#pragma unroll
        for (int k = 0; k < 8; k++) s[k] = csr_off[start + j + 8 + k];  // prefetch (overread ok)
#pragma unroll
        for (int k = 0; k < 8; k++) {
            a0 += bf_lo(uu[k].x); a1 += bf_hi(uu[k].x);
            a2 += bf_lo(uu[k].y); a3 += bf_hi(uu[k].y);
            a4 += bf_lo(uu[k].z); a5 += bf_hi(uu[k].z);
            a6 += bf_lo(uu[k].w); a7 += bf_hi(uu[k].w);
        }
    }
    float4 b0 = *(const float4*)&bias[8 * sl];
    float4 b1 = *(const float4*)&bias[8 * sl + 4];
    float r0 = fmaxf(di * a0 + b0.x, 0.f);    // ReLU folded (layer-1 epilogue)
    float r1 = fmaxf(di * a1 + b0.y, 0.f);
    float r2 = fmaxf(di * a2 + b0.z, 0.f);
    float r3 = fmaxf(di * a3 + b0.w, 0.f);
    float r4 = fmaxf(di * a4 + b1.x, 0.f);
    float r5 = fmaxf(di * a5 + b1.y, 0.f);
    float r6 = fmaxf(di * a6 + b1.z, 0.f);
    float r7 = fmaxf(di * a7 + b1.w, 0.f);
    uint4 o;
    o.x = (unsigned)f2bf(r0) | ((unsigned)f2bf(r1) << 16);
    o.y = (unsigned)f2bf(r2) | ((unsigned)f2bf(r3) << 16);
    o.z = (unsigned)f2bf(r4) | ((unsigned)f2bf(r5) << 16);
    o.w = (unsigned)f2bf(r6) | ((unsigned)f2bf(r7) << 16);
    *(uint4*)&As[(wave * 4 + g) * KP + 8 * sl] = o;   // h1 row -> LDS (garbage ok if !active)
    __syncthreads();

    // ---- Phase B: hw2 tile = dinv * (As[16x128] @ Bs^T), wave w -> cols 16w.. ----
    const int m = lane & 15, quad = lane >> 4;
    f32x4 acc = {};
    const short* arow = &As[m * KP + quad * 8];               // A row = node m
    const short* brow = &Bs[(16 * wave + m) * KP + quad * 8]; // B row = out col 16w+m
#pragma unroll
    for (int k = 0; k < 4; k++) {
        bf16x8 a = *(const bf16x8*)&arow[32 * k];
        bf16x8 b = *(const bf16x8*)&brow[32 * k];
        acc = __builtin_amdgcn_mfma_f32_16x16x32_bf16(a, b, acc, 0, 0, 0);
    }
    __syncthreads();    // done reading As -> reuse as Cs (16 x CSP shorts)
    short* Cs = As;
    float dv[4];
#pragma unroll
    for (int r = 0; r < 4; r++) {
        int gr = node0 + quad * 4 + r;
        dv[r] = dinv[gr < N ? gr : 0];
    }
#pragma unroll
    for (int r = 0; r < 4; r++)
        Cs[(quad * 4 + r) * CSP + 16 * wave + m] = (short)f2bf(acc[r] * dv[r]);
    __syncthreads();
    for (int f = tid; f < 128; f += 256) {      // 16 rows x 64 cols = 128 uint4
        int r = f >> 3, c = (f & 7) * 8;
        if (node0 + r < N)
            *(uint4*)&hw2[(size_t)(node0 + r) * 64 + c] = *(const uint4*)&Cs[r * CSP + c];
    }
}

// ==== agg64: 8 nodes/wave, 8 lanes/row, uint4 gathers + fused log_softmax ====
__global__ __launch_bounds__(256) void k_agg64b(const unsigned* __restrict__ csr_off,
                                                const int* __restrict__ rowptr,
                                                const int* __restrict__ cnt,
                                                const float* __restrict__ dinv,
                                                const unsigned char* __restrict__ xwb,
                                                const float* __restrict__ bias,
                                                float* __restrict__ out, int N) {
    const int lane = threadIdx.x & 63;
    const int wid = (blockIdx.x * blockDim.x + threadIdx.x) >> 6;
    const int g = lane >> 3, sl = lane & 7;
    const int i = wid * 8 + g;
    if (i >= N) return;
    const float di = dinv[i];
    const int slb = sl * 16;
    uint4 u = *(const uint4*)(xwb + ((size_t)i << 7) + slb);   // self row (128B rows)
    float a0 = bf_lo(u.x), a1 = bf_hi(u.x), a2 = bf_lo(u.y), a3 = bf_hi(u.y);
    float a4 = bf_lo(u.z), a5 = bf_hi(u.z), a6 = bf_lo(u.w), a7 = bf_hi(u.w);
    const int start = rowptr[i];
    const int pc = (cnt[i] + 7) & ~7;
    unsigned s[8];
#pragma unroll
    for (int k = 0; k < 8; k++) s[k] = csr_off[start + k];
    for (int j = 0; j < pc; j += 8) {
        uint4 uu[8];
#pragma unroll
        for (int k = 0; k < 8; k++) uu[k] = *(const uint4*)(xwb + (s[k] >> 1) + slb);
#pragma unroll
        for (int k = 0; k < 8; k++) s[k] = csr_off[start + j + 8 + k];
#pragma unroll
        for (int k = 0; k < 8; k++) {
            a0 += bf_lo(uu[k].x); a1 += bf_hi(uu[k].x);
            a2 += bf_lo(uu[k].y); a3 += bf_hi(uu[k].y);
            a4 += bf_lo(uu[k].z); a5 += bf_hi(uu[k].z);
            a6 += bf_lo(uu[k].w); a7 += bf_hi(uu[k].w);
        }
    }
    float4 b0 = *(const float4*)&bias[8 * sl];
    float4 b1 = *(const float4*)&bias[8 * sl + 4];
    float v0 = di * a0 + b0.x, v1 = di * a1 + b0.y;
    float v2 = di * a2 + b0.z, v3 = di * a3 + b0.w;
    float v4 = di * a4 + b1.x, v5 = di * a5 + b1.y;
    float v6 = di * a6 + b1.z, v7 = di * a7 + b1.w;
    // fused log_softmax over 64 cols (8 per lane x 8-lane group)
    float m = fmaxf(fmaxf(fmaxf(v0, v1), fmaxf(v2, v3)),
                    fmaxf(fmaxf(v4, v5), fmaxf(v6, v7)));
#pragma unroll
    for (int o = 4; o > 0; o >>= 1) m = fmaxf(m, __shfl_xor(m, o));
    float s2 = expf(v0 - m) + expf(v1 - m) + expf(v2 - m) + expf(v3 - m) +
               expf(v4 - m) + expf(v5 - m) + expf(v6 - m) + expf(v7 - m);
#pragma unroll
    for (int o = 4; o > 0; o >>= 1) s2 += __shfl_xor(s2, o);
    float ls = m + logf(s2);
    *(float4*)&out[(size_t)i * 64 + 8 * sl] = make_float4(v0 - ls, v1 - ls, v2 - ls, v3 - ls);
    *(float4*)&out[(size_t)i * 64 + 8 * sl + 4] = make_float4(v4 - ls, v5 - ls, v6 - ls, v7 - ls);
}

extern "C" void kernel_launch(void* const* d_in, const int* in_sizes, int n_in,
                              void* d_out, int out_size, void* d_ws, size_t ws_size,
                              hipStream_t stream) {
    const float* x  = (const float*)d_in[0];
    const int*   ei = (const int*)d_in[1];
    const float* W1 = (const float*)d_in[2];
    const float* b1 = (const float*)d_in[3];
    const float* W2 = (const float*)d_in[4];
    const float* b2 = (const float*)d_in[5];

    const int N = in_sizes[0] / 128;   // 100000
    const int E = in_sizes[1] / 2;     // 1600000
    const int* src = ei;
    const int* dst = ei + E;
    const int B = (N + 255) >> BSHIFT;          // 391 buckets
    const int NBLK = (E + ECHUNK - 1) / ECHUNK; // 782 edge chunks

    char* ws = (char*)d_ws;
    size_t off = 0;
    auto alloc = [&](size_t bytes) {
        void* p = ws + off;
        off += (bytes + 255) & ~(size_t)255;
        return p;
    };
    int*            bfill   = (int*)alloc(MAXB * 4);
    int*            deg     = (int*)alloc((size_t)N * 4);
    float*          dinv    = (float*)alloc((size_t)N * 4);
    int*            rowptr  = (int*)alloc((size_t)N * 4);
    unsigned*       csr_off = (unsigned*)alloc(((size_t)B * SLAB_C + 64) * 4);
    unsigned*       pairs   = (unsigned*)alloc((size_t)B * SLAB_E * 4);
    unsigned short* Wt1     = (unsigned short*)alloc(128 * 128 * 2);
    unsigned short* Wt2     = (unsigned short*)alloc(64 * 128 * 2);
    unsigned short* xw1     = (unsigned short*)alloc((size_t)(N + 1) * 128 * 2);  // +1: dummy zero row
    unsigned short* hw2     = (unsigned short*)alloc((size_t)(N + 1) * 64 * 2);   // +1: dummy zero row
    float*          outp    = (float*)d_out;

    hipMemsetAsync(bfill, 0, MAXB * 4, stream);

    // K1: castW || slab scatter (exact counts -> bfill, dst in regs)
    k_bscatter<<<NB_CAST + NBLK, THREADS, 0, stream>>>(src, dst, E, B, W1, W2, Wt1, Wt2,
                                                       bfill, pairs);
    // K2: padded CSR build from slabs (512 threads/bucket)
    k_bbuild<<<B, 512, 0, stream>>>(pairs, bfill, N, deg, dinv, rowptr, csr_off);

    // Layer 1 GEMM (prescaled)
    k_gemm1<<<(N + 63) / 64, THREADS, 0, stream>>>(
        x, Wt1, dinv, xw1, xw1 + (size_t)N * 128, N);
    // Fused layer-1 aggregation + layer-2 GEMM
    k_agg128g2<<<(N + 15) / 16, THREADS, 0, stream>>>(
        csr_off, rowptr, deg, dinv, (const unsigned char*)xw1, b1, Wt2,
        hw2, hw2 + (size_t)N * 64, N);
    // Layer-2 aggregation + fused log_softmax
    k_agg64b<<<(N + 31) / 32, THREADS, 0, stream>>>(
        csr_off, rowptr, deg, dinv, (const unsigned char*)hw2, b2, outp, N);
}

// Round 15
// 238.727 us; speedup vs baseline: 1.0302x; 1.0302x over previous
//
#include <hip/hip_runtime.h>
#include <cmath>

// GCN 2-layer forward on MI355X — FINAL (r13 verbatim, 241.6us measured best).
// r14's micro-opts (ECHUNK 2048, 512-thread bbuild, CSP pad) measured neutral-
// to-negative; reverted. Every component at verified limit:
//  - agg128+gemm2 fused (61.4us): random-gather pattern ceiling (~3.7TB/s L3
//    fill), invariant across 6 rounds; bytes minimal; slicing falsified (r11).
//  - agg64+log_softmax fused: same pattern ceiling.
//  - gemm1 MFMA, dinv prescale epilogue; CSR build via bucket slabs (floor
//    after 8 redesigns). 6 dispatches.
// Lesson bank: no mem||mem fusion (r4/r5/r10), no global node atomics (r4/r7),
// no cross-block producer/consumer (r6), keep castW pre-convert (r9),
// no column slicing (r11: 3.9x FETCH amplification).

#define THREADS 256
#define BSHIFT 8                      // 256 nodes per bucket
#define MAXB 512                      // >= ceil(N/256)
#define SLAB_E 8192                   // pairs slots per bucket
#define SLAB_C 9984                   // csr slots per bucket (SLAB_E + 256*7 pad)
#define NB_CAST 96                    // castW blocks (96*256 = 24576 weights)
#define ECHUNK 4096                   // edges per chunk (bscatter)

__device__ __forceinline__ unsigned short f2bf(float f) {
    union { float f; unsigned u; } v; v.f = f;
    unsigned r = v.u + 0x7FFFu + ((v.u >> 16) & 1u);   // round-nearest-even
    return (unsigned short)(r >> 16);
}
__device__ __forceinline__ float bf_lo(unsigned u) {
    union { unsigned u; float f; } v; v.u = u << 16; return v.f;
}
__device__ __forceinline__ float bf_hi(unsigned u) {
    union { unsigned u; float f; } v; v.u = u & 0xFFFF0000u; return v.f;
}

typedef __attribute__((ext_vector_type(8))) short bf16x8;
typedef __attribute__((ext_vector_type(4))) float f32x4;

// ==== K1: castW (blocks 0..95) || slab scatter (blocks 96..) ====
__global__ __launch_bounds__(256) void k_bscatter(const int* __restrict__ src,
                                                  const int* __restrict__ dst, int E, int B,
                                                  const float* __restrict__ W1,
                                                  const float* __restrict__ W2,
                                                  unsigned short* __restrict__ Wt1,
                                                  unsigned short* __restrict__ Wt2,
                                                  int* __restrict__ bfill,
                                                  unsigned* __restrict__ pairs) {
    const int tid = threadIdx.x;
    if (blockIdx.x < NB_CAST) {
        // Wt1[n][k] = bf16(W1[k][n]) (128x128), Wt2[n][k] = bf16(W2[k][n]) (64x128)
        int idx = blockIdx.x * 256 + tid;
        if (idx < 16384) {
            int n = idx >> 7, k = idx & 127;
            Wt1[idx] = f2bf(W1[k * 128 + n]);
        } else {
            int t = idx - 16384;
            int n = t >> 7, k = t & 127;
            Wt2[t] = f2bf(W2[k * 64 + n]);
        }
        return;
    }
    __shared__ int lc[MAXB];     // per-block bucket count, then per-bucket rank
    __shared__ int lbase[MAXB];  // reservation base within bucket slab
    const int e0 = (blockIdx.x - NB_CAST) * ECHUNK;
    for (int i = tid; i < MAXB; i += 256) lc[i] = 0;
    __syncthreads();
#pragma unroll
    for (int k = 0; k < ECHUNK / 1024; k++) {
        int e = e0 + k * 1024 + tid * 4;            // E % 4 == 0
        if (e < E) {
            int4 d4 = *(const int4*)&dst[e];
            atomicAdd(&lc[d4.x >> BSHIFT], 1); atomicAdd(&lc[d4.y >> BSHIFT], 1);
            atomicAdd(&lc[d4.z >> BSHIFT], 1); atomicAdd(&lc[d4.w >> BSHIFT], 1);
        }
    }
    __syncthreads();
    for (int b = tid; b < B; b += 256)
        lbase[b] = lc[b] ? atomicAdd(&bfill[b], lc[b]) : 0;
    __syncthreads();
    for (int i = tid; i < MAXB; i += 256) lc[i] = 0;  // reuse as rank
    __syncthreads();
#pragma unroll
    for (int k = 0; k < ECHUNK / 1024; k++) {
        int e = e0 + k * 1024 + tid * 4;
        if (e < E) {
            int4 s4 = *(const int4*)&src[e];
            int4 d4 = *(const int4*)&dst[e];
            int b0, r;
            b0 = d4.x >> BSHIFT; r = atomicAdd(&lc[b0], 1);
            pairs[(size_t)b0 * SLAB_E + lbase[b0] + r] = ((unsigned)(d4.x & 255) << 24) | (unsigned)s4.x;
            b0 = d4.y >> BSHIFT; r = atomicAdd(&lc[b0], 1);
            pairs[(size_t)b0 * SLAB_E + lbase[b0] + r] = ((unsigned)(d4.y & 255) << 24) | (unsigned)s4.y;
            b0 = d4.z >> BSHIFT; r = atomicAdd(&lc[b0], 1);
            pairs[(size_t)b0 * SLAB_E + lbase[b0] + r] = ((unsigned)(d4.z & 255) << 24) | (unsigned)s4.z;
            b0 = d4.w >> BSHIFT; r = atomicAdd(&lc[b0], 1);
            pairs[(size_t)b0 * SLAB_E + lbase[b0] + r] = ((unsigned)(d4.w & 255) << 24) | (unsigned)s4.w;
        }
    }
}

// ==== K2: per-bucket padded-CSR build: one block per bucket (slab-based) ====
__global__ __launch_bounds__(256) void k_bbuild(const unsigned* __restrict__ pairs,
                                                const int* __restrict__ bfill, int N,
                                                int* __restrict__ deg,
                                                float* __restrict__ dinv,
                                                int* __restrict__ rowptr,
                                                unsigned* __restrict__ csr_off) {
    __shared__ int ldeg[256], lex[256], lrank[256];
    const int b = blockIdx.x, tid = threadIdx.x;
    const int node0 = b << BSHIFT;
    const unsigned* pb = pairs + (size_t)b * SLAB_E;
    const int cnt_e = bfill[b];
    const int pbase = b * SLAB_C;
    ldeg[tid] = 0;
    __syncthreads();
    for (int e = tid; e < cnt_e; e += 256)
        atomicAdd(&ldeg[pb[e] >> 24], 1);
    __syncthreads();
    int v = ldeg[tid];
    int pd = (v + 7) & ~7;                       // padded degree
    lex[tid] = pd; __syncthreads();
    for (int o = 1; o < 256; o <<= 1) {
        int add = (tid >= o) ? lex[tid - o] : 0;
        __syncthreads();
        lex[tid] += add;
        __syncthreads();
    }
    int pexcl = lex[tid] - pd;                   // exclusive scan of padded degrees
    if (node0 + tid < N) {
        deg[node0 + tid] = v;
        dinv[node0 + tid] = rsqrtf((float)(v + 1));
        rowptr[node0 + tid] = pbase + pexcl;
    }
    __syncthreads();
    lex[tid] = pexcl;      // keep padded exclusive offsets for the scatter
    lrank[tid] = 0;
    __syncthreads();
    for (int e = tid; e < cnt_e; e += 256) {
        unsigned p = pb[e];
        int loc = p >> 24;
        int r = atomicAdd(&lrank[loc], 1);
        csr_off[pbase + lex[loc] + r] = (p & 0xFFFFFFu) << 8;   // byte offset (256B rows)
    }
    // fill pad slots with the dummy source (row N is all-zeros)
    for (int p = v; p < pd; p++)
        csr_off[pbase + pexcl + p] = ((unsigned)N) << 8;
}

// ==== gemm1: xw1[M x 128](bf16) = dinv[row] * (x[M x 128] @ Wt1^T) ====
__global__ __launch_bounds__(256) void k_gemm1(const float* __restrict__ A,
                                               const unsigned short* __restrict__ Wt,
                                               const float* __restrict__ dinv,
                                               unsigned short* __restrict__ Out,
                                               unsigned short* __restrict__ zrow,
                                               int M) {
    constexpr int NC = 128, KP = 136;
    __shared__ __align__(16) short Bs[NC * KP];
    const int tid = threadIdx.x;
    const int row0 = blockIdx.x * 64;

    if (blockIdx.x == 0 && tid < NC) zrow[tid] = 0;   // dummy zero row

    for (int f = tid; f < NC * 16; f += 256) {
        int n = f >> 4, c = (f & 15) * 8;
        *(uint4*)&Bs[n * KP + c] = *(const uint4*)&Wt[n * 128 + c];
    }

    const int wave = tid >> 6, lane = tid & 63;
    const int m = lane & 15, quad = lane >> 4;
    const int row = row0 + 16 * wave + m;
    const int rowc = row < M ? row : (M - 1);          // clamp; masked at store

    bf16x8 afr[4];
#pragma unroll
    for (int k = 0; k < 4; k++) {
        float4 lo = *(const float4*)&A[(size_t)rowc * 128 + quad * 8 + 32 * k];
        float4 hi = *(const float4*)&A[(size_t)rowc * 128 + quad * 8 + 32 * k + 4];
        bf16x8 a;
        a[0] = (short)f2bf(lo.x); a[1] = (short)f2bf(lo.y);
        a[2] = (short)f2bf(lo.z); a[3] = (short)f2bf(lo.w);
        a[4] = (short)f2bf(hi.x); a[5] = (short)f2bf(hi.y);
        a[6] = (short)f2bf(hi.z); a[7] = (short)f2bf(hi.w);
        afr[k] = a;
    }
    __syncthreads();    // Bs ready

    constexpr int CT = NC / 16;
    f32x4 acc[CT] = {};
    const short* brow = &Bs[m * KP + quad * 8];
#pragma unroll
    for (int k = 0; k < 4; k++) {
#pragma unroll
        for (int c = 0; c < CT; c++) {
            bf16x8 b = *(const bf16x8*)&brow[(size_t)c * 16 * KP + 32 * k];
            acc[c] = __builtin_amdgcn_mfma_f32_16x16x32_bf16(afr[k], b, acc[c], 0, 0, 0);
        }
    }

    __syncthreads();    // all waves done reading Bs -> reuse as Cs
    short* Cs = Bs;
    const int rbase = 16 * wave + quad * 4;
    float dv[4];
#pragma unroll
    for (int r = 0; r < 4; r++) {
        int gr = row0 + rbase + r;
        dv[r] = dinv[gr < M ? gr : 0];
    }
#pragma unroll
    for (int c = 0; c < CT; c++)
#pragma unroll
        for (int r = 0; r < 4; r++)
            Cs[(rbase + r) * NC + 16 * c + m] = (short)f2bf(acc[c][r] * dv[r]);
    __syncthreads();
    for (int f = tid; f < 64 * NC / 8; f += 256) {
        int r = f / (NC / 8), c = (f % (NC / 8)) * 8;
        if (row0 + r < M)
            *(uint4*)&Out[(size_t)(row0 + r) * NC + c] = *(const uint4*)&Cs[r * NC + c];
    }
}

// ==== FUSED agg128 + gemm2: per block of 16 nodes ====
// Phase A (aggregation): 4 nodes/wave, 16 lanes/row, uint4 gathers from xw1
// (pre-scaled), bias+ReLU -> h1 row staged in LDS (never hits global).
// Phase B (MFMA): hw2[16 x 64] = dinv[row] * (h1_tile @ Wt2^T); wave w computes
// cols [16w, 16w+16). Coalesced store via LDS transpose.
__global__ __launch_bounds__(256) void k_agg128g2(const unsigned* __restrict__ csr_off,
                                                  const int* __restrict__ rowptr,
                                                  const int* __restrict__ cnt,
                                                  const float* __restrict__ dinv,
                                                  const unsigned char* __restrict__ xwb,
                                                  const float* __restrict__ bias,
                                                  const unsigned short* __restrict__ Wt2,
                                                  unsigned short* __restrict__ hw2,
                                                  unsigned short* __restrict__ zrow,
                                                  int N) {
    constexpr int KP = 136;
    __shared__ __align__(16) short Bs[64 * KP];   // Wt2 tile (17.4 KB)
    __shared__ __align__(16) short As[16 * KP];   // h1 rows / Cs (4.4 KB)
    const int tid = threadIdx.x;
    const int lane = tid & 63, wave = tid >> 6;
    const int g = lane >> 4, sl = lane & 15;
    const int node0 = blockIdx.x * 16;
    const int i = node0 + wave * 4 + g;
    const bool active = (i < N);
    const int ic = active ? i : 0;

    if (blockIdx.x == 0 && tid < 64) zrow[tid] = 0;   // dummy zero row of hw2

    // stage Wt2 (64 x 128 bf16)
    for (int f = tid; f < 64 * 16; f += 256) {
        int n = f >> 4, c = (f & 15) * 8;
        *(uint4*)&Bs[n * KP + c] = *(const uint4*)&Wt2[n * 128 + c];
    }

    // ---- Phase A: aggregate node i, cols 8sl..8sl+7 ----
    const float di = dinv[ic];
    const int slb = sl * 16;
    uint4 u = *(const uint4*)(xwb + ((size_t)ic << 8) + slb);  // self row (pre-scaled)
    float a0 = bf_lo(u.x), a1 = bf_hi(u.x), a2 = bf_lo(u.y), a3 = bf_hi(u.y);
    float a4 = bf_lo(u.z), a5 = bf_hi(u.z), a6 = bf_lo(u.w), a7 = bf_hi(u.w);
    const int start = rowptr[ic];
    const int pc = active ? ((cnt[ic] + 7) & ~7) : 0;
    unsigned s[8];
#pragma unroll
    for (int k = 0; k < 8; k++) s[k] = csr_off[start + k];
    for (int j = 0; j < pc; j += 8) {
        uint4 uu[8];
#pragma unroll
        for (int k = 0; k < 8; k++) uu[k] = *(const uint4*)(xwb + s[k] + slb);
#pragma unroll
        for (int k = 0; k < 8; k++) s[k] = csr_off[start + j + 8 + k];  // prefetch (overread ok)
#pragma unroll
        for (int k = 0; k < 8; k++) {
            a0 += bf_lo(uu[k].x); a1 += bf_hi(uu[k].x);
            a2 += bf_lo(uu[k].y); a3 += bf_hi(uu[k].y);
            a4 += bf_lo(uu[k].z); a5 += bf_hi(uu[k].z);
            a6 += bf_lo(uu[k].w); a7 += bf_hi(uu[k].w);
        }
    }
    float4 b0 = *(const float4*)&bias[8 * sl];
    float4 b1 = *(const float4*)&bias[8 * sl + 4];
    float r0 = fmaxf(di * a0 + b0.x, 0.f);    // ReLU folded (layer-1 epilogue)
    float r1 = fmaxf(di * a1 + b0.y, 0.f);
    float r2 = fmaxf(di * a2 + b0.z, 0.f);
    float r3 = fmaxf(di * a3 + b0.w, 0.f);
    float r4 = fmaxf(di * a4 + b1.x, 0.f);
    float r5 = fmaxf(di * a5 + b1.y, 0.f);
    float r6 = fmaxf(di * a6 + b1.z, 0.f);
    float r7 = fmaxf(di * a7 + b1.w, 0.f);
    uint4 o;
    o.x = (unsigned)f2bf(r0) | ((unsigned)f2bf(r1) << 16);
    o.y = (unsigned)f2bf(r2) | ((unsigned)f2bf(r3) << 16);
    o.z = (unsigned)f2bf(r4) | ((unsigned)f2bf(r5) << 16);
    o.w = (unsigned)f2bf(r6) | ((unsigned)f2bf(r7) << 16);
    *(uint4*)&As[(wave * 4 + g) * KP + 8 * sl] = o;   // h1 row -> LDS (garbage ok if !active)
    __syncthreads();

    // ---- Phase B: hw2 tile = dinv * (As[16x128] @ Bs^T), wave w -> cols 16w.. ----
    const int m = lane & 15, quad = lane >> 4;
    f32x4 acc = {};
    const short* arow = &As[m * KP + quad * 8];               // A row = node m
    const short* brow = &Bs[(16 * wave + m) * KP + quad * 8]; // B row = out col 16w+m
#pragma unroll
    for (int k = 0; k < 4; k++) {
        bf16x8 a = *(const bf16x8*)&arow[32 * k];
        bf16x8 b = *(const bf16x8*)&brow[32 * k];
        acc = __builtin_amdgcn_mfma_f32_16x16x32_bf16(a, b, acc, 0, 0, 0);
    }
    __syncthreads();    // done reading As -> reuse as Cs (16 x 64 shorts)
    short* Cs = As;
    float dv[4];
#pragma unroll
    for (int r = 0; r < 4; r++) {
        int gr = node0 + quad * 4 + r;
        dv[r] = dinv[gr < N ? gr : 0];
    }
#pragma unroll
    for (int r = 0; r < 4; r++)
        Cs[(quad * 4 + r) * 64 + 16 * wave + m] = (short)f2bf(acc[r] * dv[r]);
    __syncthreads();
    for (int f = tid; f < 128; f += 256) {      // 16 rows x 64 cols = 128 uint4
        int r = f >> 3, c = (f & 7) * 8;
        if (node0 + r < N)
            *(uint4*)&hw2[(size_t)(node0 + r) * 64 + c] = *(const uint4*)&Cs[r * 64 + c];
    }
}

// ==== agg64: 8 nodes/wave, 8 lanes/row, uint4 gathers + fused log_softmax ====
__global__ __launch_bounds__(256) void k_agg64b(const unsigned* __restrict__ csr_off,
                                                const int* __restrict__ rowptr,
                                                const int* __restrict__ cnt,
                                                const float* __restrict__ dinv,
                                                const unsigned char* __restrict__ xwb,
                                                const float* __restrict__ bias,
                                                float* __restrict__ out, int N) {
    const int lane = threadIdx.x & 63;
    const int wid = (blockIdx.x * blockDim.x + threadIdx.x) >> 6;
    const int g = lane >> 3, sl = lane & 7;
    const int i = wid * 8 + g;
    if (i >= N) return;
    const float di = dinv[i];
    const int slb = sl * 16;
    uint4 u = *(const uint4*)(xwb + ((size_t)i << 7) + slb);   // self row (128B rows)
    float a0 = bf_lo(u.x), a1 = bf_hi(u.x), a2 = bf_lo(u.y), a3 = bf_hi(u.y);
    float a4 = bf_lo(u.z), a5 = bf_hi(u.z), a6 = bf_lo(u.w), a7 = bf_hi(u.w);
    const int start = rowptr[i];
    const int pc = (cnt[i] + 7) & ~7;
    unsigned s[8];
#pragma unroll
    for (int k = 0; k < 8; k++) s[k] = csr_off[start + k];
    for (int j = 0; j < pc; j += 8) {
        uint4 uu[8];
#pragma unroll
        for (int k = 0; k < 8; k++) uu[k] = *(const uint4*)(xwb + (s[k] >> 1) + slb);
#pragma unroll
        for (int k = 0; k < 8; k++) s[k] = csr_off[start + j + 8 + k];
#pragma unroll
        for (int k = 0; k < 8; k++) {
            a0 += bf_lo(uu[k].x); a1 += bf_hi(uu[k].x);
            a2 += bf_lo(uu[k].y); a3 += bf_hi(uu[k].y);
            a4 += bf_lo(uu[k].z); a5 += bf_hi(uu[k].z);
            a6 += bf_lo(uu[k].w); a7 += bf_hi(uu[k].w);
        }
    }
    float4 b0 = *(const float4*)&bias[8 * sl];
    float4 b1 = *(const float4*)&bias[8 * sl + 4];
    float v0 = di * a0 + b0.x, v1 = di * a1 + b0.y;
    float v2 = di * a2 + b0.z, v3 = di * a3 + b0.w;
    float v4 = di * a4 + b1.x, v5 = di * a5 + b1.y;
    float v6 = di * a6 + b1.z, v7 = di * a7 + b1.w;
    // fused log_softmax over 64 cols (8 per lane x 8-lane group)
    float m = fmaxf(fmaxf(fmaxf(v0, v1), fmaxf(v2, v3)),
                    fmaxf(fmaxf(v4, v5), fmaxf(v6, v7)));
#pragma unroll
    for (int o = 4; o > 0; o >>= 1) m = fmaxf(m, __shfl_xor(m, o));
    float s2 = expf(v0 - m) + expf(v1 - m) + expf(v2 - m) + expf(v3 - m) +
               expf(v4 - m) + expf(v5 - m) + expf(v6 - m) + expf(v7 - m);
#pragma unroll
    for (int o = 4; o > 0; o >>= 1) s2 += __shfl_xor(s2, o);
    float ls = m + logf(s2);
    *(float4*)&out[(size_t)i * 64 + 8 * sl] = make_float4(v0 - ls, v1 - ls, v2 - ls, v3 - ls);
    *(float4*)&out[(size_t)i * 64 + 8 * sl + 4] = make_float4(v4 - ls, v5 - ls, v6 - ls, v7 - ls);
}

extern "C" void kernel_launch(void* const* d_in, const int* in_sizes, int n_in,
                              void* d_out, int out_size, void* d_ws, size_t ws_size,
                              hipStream_t stream) {
    const float* x  = (const float*)d_in[0];
    const int*   ei = (const int*)d_in[1];
    const float* W1 = (const float*)d_in[2];
    const float* b1 = (const float*)d_in[3];
    const float* W2 = (const float*)d_in[4];
    const float* b2 = (const float*)d_in[5];

    const int N = in_sizes[0] / 128;   // 100000
    const int E = in_sizes[1] / 2;     // 1600000
    const int* src = ei;
    const int* dst = ei + E;
    const int B = (N + 255) >> BSHIFT;          // 391 buckets
    const int NBLK = (E + ECHUNK - 1) / ECHUNK; // 391 edge chunks

    char* ws = (char*)d_ws;
    size_t off = 0;
    auto alloc = [&](size_t bytes) {
        void* p = ws + off;
        off += (bytes + 255) & ~(size_t)255;
        return p;
    };
    int*            bfill   = (int*)alloc(MAXB * 4);
    int*            deg     = (int*)alloc((size_t)N * 4);
    float*          dinv    = (float*)alloc((size_t)N * 4);
    int*            rowptr  = (int*)alloc((size_t)N * 4);
    unsigned*       csr_off = (unsigned*)alloc(((size_t)B * SLAB_C + 64) * 4);
    unsigned*       pairs   = (unsigned*)alloc((size_t)B * SLAB_E * 4);
    unsigned short* Wt1     = (unsigned short*)alloc(128 * 128 * 2);
    unsigned short* Wt2     = (unsigned short*)alloc(64 * 128 * 2);
    unsigned short* xw1     = (unsigned short*)alloc((size_t)(N + 1) * 128 * 2);  // +1: dummy zero row
    unsigned short* hw2     = (unsigned short*)alloc((size_t)(N + 1) * 64 * 2);   // +1: dummy zero row
    float*          outp    = (float*)d_out;

    hipMemsetAsync(bfill, 0, MAXB * 4, stream);

    // K1: castW || slab scatter (exact counts -> bfill)
    k_bscatter<<<NB_CAST + NBLK, THREADS, 0, stream>>>(src, dst, E, B, W1, W2, Wt1, Wt2,
                                                       bfill, pairs);
    // K2: padded CSR build from slabs (deg, dinv, rowptr, csr_off)
    k_bbuild<<<B, THREADS, 0, stream>>>(pairs, bfill, N, deg, dinv, rowptr, csr_off);

    // Layer 1 GEMM (prescaled)
    k_gemm1<<<(N + 63) / 64, THREADS, 0, stream>>>(
        x, Wt1, dinv, xw1, xw1 + (size_t)N * 128, N);
    // Fused layer-1 aggregation + layer-2 GEMM
    k_agg128g2<<<(N + 15) / 16, THREADS, 0, stream>>>(
        csr_off, rowptr, deg, dinv, (const unsigned char*)xw1, b1, Wt2,
        hw2, hw2 + (size_t)N * 64, N);
    // Layer-2 aggregation + fused log_softmax
    k_agg64b<<<(N + 31) / 32, THREADS, 0, stream>>>(
        csr_off, rowptr, deg, dinv, (const unsigned char*)hw2, b2, outp, N);
}